// Round 5
// baseline (155.934 us; speedup 1.0000x reference)
//
#include <hip/hip_runtime.h>
#include <hip/hip_bf16.h>

// Wave-independent version: 1024 blocks x 64 threads (1 wave). No
// __syncthreads anywhere -> no vmcnt(0) barrier drains, no phase alignment.
// Each wave owns rows [blk*256, +256): stages its own weight copy in LDS,
// computes its own cumprev (uniform scalar loads for the inner loop), runs
// the packed-fp32 MLP (4 rows/lane as two <2 x float> pairs), and stores its
// 102,400 B chunk (1024B-aligned) as 100 full-wave 64x16B contiguous stores
// -> every 128B line written exactly once (WRITE_SIZE = ideal 102,400 KB).
// Waves slip freely: first store issues at ~2.5us and the HBM write queue
// stays fed while later waves compute -> total ~= drain(16us) + small head.

typedef float f2 __attribute__((ext_vector_type(2)));
typedef float f4 __attribute__((ext_vector_type(4)));

#define NBLOCKS 1024

// LDS float offsets (per 1-wave block, ~6.7 KB)
#define OFF_W2 0      // [k*32+i]=W2[i][k] i<30; +30=b2[k]; +31=W3[k]  (960)
#define OFF_W1 960    // [k*8+i]=W1[i][k] i<4; +4=b1[k]; pads 0        (240)
#define OFF_PM 1200   // Pmax[100] (16B-aligned base)
#define OFF_CP 1312   // cumprev[100] (16B-aligned base)
#define OFF_TD 1424   // td[256 rows]
#define SMEM_FLOATS (OFF_TD + 256)

__device__ __forceinline__ f2 splat2(float v) { return (f2){v, v}; }

__global__ __launch_bounds__(64, 2) void e2e_mlp_fused_kernel(
    const float* __restrict__ x,    const float* __restrict__ Cost,
    const float* __restrict__ Pmax, const float* __restrict__ Pd,
    const float* __restrict__ wcapp,const float* __restrict__ W1,
    const float* __restrict__ b1,   const float* __restrict__ W2,
    const float* __restrict__ b2,   const float* __restrict__ W3,
    const float* __restrict__ b3p,  float* __restrict__ out) {
  __shared__ float s[SMEM_FLOATS];
  const int lane = threadIdx.x;           // 0..63, one wave per block
  const long wrow = (long)blockIdx.x * 256;

  // x loads first (latency hidden under staging / cumprev).
  const float4* __restrict__ x4 = (const float4*)x;
  const float4 xA0 = x4[wrow + lane];
  const float4 xA1 = x4[wrow + 64 + lane];
  const float4 xB0 = x4[wrow + 128 + lane];
  const float4 xB1 = x4[wrow + 192 + lane];

  // ---- stage weights (transposed+padded) into this wave's LDS ----
  for (int idx = lane; idx < 960; idx += 64) {
    const int k = idx >> 5, i = idx & 31;
    float v;
    if (i < 30)       v = W2[i * 30 + k];
    else if (i == 30) v = b2[k];
    else              v = W3[k];
    s[OFF_W2 + idx] = v;
  }
  for (int idx = lane; idx < 240; idx += 64) {
    const int k = idx >> 3, i = idx & 7;
    float v = 0.0f;
    if (i < 4)       v = W1[i * 30 + k];
    else if (i == 4) v = b1[k];
    s[OFF_W1 + idx] = v;
  }
  if (lane < 50) {
    s[OFF_PM + lane]      = Pmax[lane];
    s[OFF_PM + 50 + lane] = Pmax[50 + lane];
  }

  // ---- sum(Pd): lanes 0..24 float4 partials, shuffle reduce, broadcast ----
  float p = 0.0f;
  if (lane < 25) {
    const float4 q = ((const float4*)Pd)[lane];
    p = q.x + q.y + q.z + q.w;
  }
#pragma unroll
  for (int off = 32; off; off >>= 1) p += __shfl_down(p, off, 64);
  const float spd = __shfl(p, 0, 64);

  // ---- cumprev (per-wave redundant; stable tie-break == jnp argsort) ----
  // j = lane and j = 64+lane (lane<36). Inner-loop Cost[i]/Pmax[i] are
  // uniform-address -> scalar loads (off the LDS pipe, L1-cached).
  {
    const float cj = Cost[lane];
    float cj2 = 0.0f;
    if (lane < 36) cj2 = Cost[64 + lane];
    float acc = 0.0f, acc2 = 0.0f;
    for (int i = 0; i < 100; ++i) {
      const float ci = Cost[i];
      const float pi = Pmax[i];
      acc  += ((ci < cj)  || (ci == cj  && i < lane))      ? pi : 0.0f;
      acc2 += ((ci < cj2) || (ci == cj2 && i < 64 + lane)) ? pi : 0.0f;
    }
    s[OFF_CP + lane] = acc;
    if (lane < 36) s[OFF_CP + 64 + lane] = acc2;
  }

  // ---- MLP layer 1 (packed f2: pair A = rows lane/lane+64, B = +128/+192) --
  const f2 zero = {0.0f, 0.0f};
  const f2 Ax = {xA0.x, xA1.x}, Ay = {xA0.y, xA1.y};
  const f2 Az = {xA0.z, xA1.z}, Aw = {xA0.w, xA1.w};
  const f2 Bx = {xB0.x, xB1.x}, By = {xB0.y, xB1.y};
  const f2 Bz = {xB0.z, xB1.z}, Bw = {xB0.w, xB1.w};

  f2 h1a[30], h1b[30];
#pragma unroll
  for (int k = 0; k < 30; ++k) {
    const float4 wv = *(const float4*)&s[OFF_W1 + k * 8];
    const float bb = s[OFF_W1 + k * 8 + 4];
    f2 pa = splat2(bb), pb = splat2(bb);
    pa = __builtin_elementwise_fma(Ax, splat2(wv.x), pa);
    pb = __builtin_elementwise_fma(Bx, splat2(wv.x), pb);
    pa = __builtin_elementwise_fma(Ay, splat2(wv.y), pa);
    pb = __builtin_elementwise_fma(By, splat2(wv.y), pb);
    pa = __builtin_elementwise_fma(Az, splat2(wv.z), pa);
    pb = __builtin_elementwise_fma(Bz, splat2(wv.z), pb);
    pa = __builtin_elementwise_fma(Aw, splat2(wv.w), pa);
    pb = __builtin_elementwise_fma(Bw, splat2(wv.w), pb);
    h1a[k] = __builtin_elementwise_max(pa, zero);
    h1b[k] = __builtin_elementwise_max(pb, zero);
  }

  // ---- layer 2 + output (W2 column k via LDS b128 broadcasts) ----
  f2 yA = zero, yB = zero;
#pragma unroll 2
  for (int k = 0; k < 30; ++k) {
    const float4* __restrict__ wr = (const float4*)&s[OFF_W2 + k * 32];
    f2 sa = zero, sb = zero, sa2 = zero, sb2 = zero;
#pragma unroll
    for (int c = 0; c < 7; ++c) {
      const float4 wv = wr[c];
      sa  = __builtin_elementwise_fma(h1a[4 * c],     splat2(wv.x), sa);
      sb  = __builtin_elementwise_fma(h1b[4 * c],     splat2(wv.x), sb);
      sa2 = __builtin_elementwise_fma(h1a[4 * c + 1], splat2(wv.y), sa2);
      sb2 = __builtin_elementwise_fma(h1b[4 * c + 1], splat2(wv.y), sb2);
      sa  = __builtin_elementwise_fma(h1a[4 * c + 2], splat2(wv.z), sa);
      sb  = __builtin_elementwise_fma(h1b[4 * c + 2], splat2(wv.z), sb);
      sa2 = __builtin_elementwise_fma(h1a[4 * c + 3], splat2(wv.w), sa2);
      sb2 = __builtin_elementwise_fma(h1b[4 * c + 3], splat2(wv.w), sb2);
    }
    const float4 w7 = wr[7];  // {W2[28][k], W2[29][k], b2[k], W3[k]}
    sa  = __builtin_elementwise_fma(h1a[28], splat2(w7.x), sa);
    sb  = __builtin_elementwise_fma(h1b[28], splat2(w7.x), sb);
    sa2 = __builtin_elementwise_fma(h1a[29], splat2(w7.y), sa2);
    sb2 = __builtin_elementwise_fma(h1b[29], splat2(w7.y), sb2);
    f2 hA = __builtin_elementwise_max(sa + sa2 + splat2(w7.z), zero);
    f2 hB = __builtin_elementwise_max(sb + sb2 + splat2(w7.z), zero);
    yA = __builtin_elementwise_fma(hA, splat2(w7.w), yA);
    yB = __builtin_elementwise_fma(hB, splat2(w7.w), yB);
  }

  // total_d = sum(Pd) - wc*(y + b3) -> wave-private LDS exchange
  const float wc = wcapp[0];
  const float Aconst = spd - wc * b3p[0];
  s[OFF_TD + lane]       = Aconst - wc * yA.x;
  s[OFF_TD + lane + 64]  = Aconst - wc * yA.y;
  s[OFF_TD + lane + 128] = Aconst - wc * yB.x;
  s[OFF_TD + lane + 192] = Aconst - wc * yB.y;
  // (same-wave LDS write->read: ordered by lgkmcnt, no barrier needed)

  // ---- store phase: full-line coverage, no barrier before it ----
  // Wave chunk = bytes [wrow*400, +102400), 1024B-aligned. Iteration it:
  // lane writes bytes [it*1024 + lane*16, +16). row=o/400, colgrp=(o%400)/16.
  {
    const int o0 = lane * 16;
    int r = o0 / 400;            // 0..2
    int m = o0 - 400 * r;        // o mod 400
    float* __restrict__ op = out + wrow * 100 + lane * 4;
#pragma unroll 4
    for (int it = 0; it < 100; ++it) {
      const float td = s[OFF_TD + r];
      const int c16 = m >> 4;    // 0..24
      const f4 cpr = *(const f4*)&s[OFF_CP + 4 * c16];
      const f4 pmx = *(const f4*)&s[OFF_PM + 4 * c16];
      f4 v = (f4){td, td, td, td} - cpr;
      v = __builtin_elementwise_max(v, (f4){0.0f, 0.0f, 0.0f, 0.0f});
      v = __builtin_elementwise_min(v, pmx);
      *(f4*)op = v;
      op += 256;                 // +1024 B
      m += 224;                  // 1024 mod 400
      r += 2;
      if (m >= 400) { m -= 400; r += 1; }
    }
  }
}

extern "C" void kernel_launch(void* const* d_in, const int* in_sizes, int n_in,
                              void* d_out, int out_size, void* d_ws, size_t ws_size,
                              hipStream_t stream) {
  const float* x    = (const float*)d_in[0];
  const float* Cost = (const float*)d_in[1];
  const float* Pmax = (const float*)d_in[2];
  const float* Pd   = (const float*)d_in[3];
  const float* wcap = (const float*)d_in[4];
  const float* W1   = (const float*)d_in[5];
  const float* b1   = (const float*)d_in[6];
  const float* W2   = (const float*)d_in[7];
  const float* b2   = (const float*)d_in[8];
  const float* W3   = (const float*)d_in[9];
  const float* b3   = (const float*)d_in[10];
  float* out = (float*)d_out;

  e2e_mlp_fused_kernel<<<NBLOCKS, 64, 0, stream>>>(
      x, Cost, Pmax, Pd, wcap, W1, b1, W2, b2, W3, b3, out);
}